// Round 2
// baseline (432.217 us; speedup 1.0000x reference)
//
#include <hip/hip_runtime.h>
#include <stdint.h>

#define B_  4
#define S_  1024
#define D_  1024
#define H_  16
#define HD_ 64
#define E_  2048   // 2*D
#define C2_ 128    // 2*HD

typedef __attribute__((ext_vector_type(8))) short          bf16x8;  // MFMA A/B frag (8 bf16)
typedef __attribute__((ext_vector_type(8))) unsigned short u16x8;
typedef __attribute__((ext_vector_type(4))) unsigned short u16x4;
typedef __attribute__((ext_vector_type(4))) float          f32x4;   // MFMA C/D frag

__device__ __forceinline__ unsigned short f2bf(float f) {
  union { float f; unsigned int u; } v; v.f = f;
  unsigned int r = v.u + 0x7fffu + ((v.u >> 16) & 1u);   // RNE
  return (unsigned short)(r >> 16);
}

// 16-lane (DPP row) reductions — VALU only, keeps the DS pipe free.
__device__ __forceinline__ float red16_max(float x) {
  x = fmaxf(x, __int_as_float(__builtin_amdgcn_mov_dpp(__float_as_int(x), 0xB1, 0xF, 0xF, false)));
  x = fmaxf(x, __int_as_float(__builtin_amdgcn_mov_dpp(__float_as_int(x), 0x4E, 0xF, 0xF, false)));
  x = fmaxf(x, __int_as_float(__builtin_amdgcn_mov_dpp(__float_as_int(x), 0x141, 0xF, 0xF, false)));
  x = fmaxf(x, __int_as_float(__builtin_amdgcn_mov_dpp(__float_as_int(x), 0x140, 0xF, 0xF, false)));
  return x;
}
__device__ __forceinline__ float red16_sum(float x) {
  x += __int_as_float(__builtin_amdgcn_mov_dpp(__float_as_int(x), 0xB1, 0xF, 0xF, false));
  x += __int_as_float(__builtin_amdgcn_mov_dpp(__float_as_int(x), 0x4E, 0xF, 0xF, false));
  x += __int_as_float(__builtin_amdgcn_mov_dpp(__float_as_int(x), 0x141, 0xF, 0xF, false));
  x += __int_as_float(__builtin_amdgcn_mov_dpp(__float_as_int(x), 0x140, 0xF, 0xF, false));
  return x;
}

// ---------------- LayerNorm (D=1024) + bf16 cast ----------------
__global__ __launch_bounds__(256) void ln_cast_k(const float* __restrict__ x,
                                                 const float* __restrict__ g,
                                                 const float* __restrict__ bb,
                                                 unsigned short* __restrict__ out) {
  int row = blockIdx.x;
  int tid = threadIdx.x;
  const float* xr = x + (size_t)row * D_;
  float4 xv = *(const float4*)(xr + tid * 4);
  float s  = xv.x + xv.y + xv.z + xv.w;
  float sq = xv.x * xv.x + xv.y * xv.y + xv.z * xv.z + xv.w * xv.w;
#pragma unroll
  for (int m = 32; m; m >>= 1) { s += __shfl_xor(s, m, 64); sq += __shfl_xor(sq, m, 64); }
  __shared__ float ps[4], pq[4];
  int w = tid >> 6, l = tid & 63;
  if (l == 0) { ps[w] = s; pq[w] = sq; }
  __syncthreads();
  s  = ps[0] + ps[1] + ps[2] + ps[3];
  sq = pq[0] + pq[1] + pq[2] + pq[3];
  float mean = s * (1.f / D_);
  float var  = sq * (1.f / D_) - mean * mean;
  float rstd = rsqrtf(var + 1e-5f);
  float4 gv = *(const float4*)(g + tid * 4);
  float4 bv = *(const float4*)(bb + tid * 4);
  u16x4 o;
  o.x = f2bf((xv.x - mean) * rstd * gv.x + bv.x);
  o.y = f2bf((xv.y - mean) * rstd * gv.y + bv.y);
  o.z = f2bf((xv.z - mean) * rstd * gv.z + bv.z);
  o.w = f2bf((xv.w - mean) * rstd * gv.w + bv.w);
  *(u16x4*)(out + (size_t)row * D_ + tid * 4) = o;
}

// ---------------- fp32 -> bf16 cast (weights) ----------------
__global__ __launch_bounds__(256) void cast_k(const float* __restrict__ in,
                                              unsigned short* __restrict__ out, int n4) {
  int i = blockIdx.x * 256 + threadIdx.x;
  if (i < n4) {
    float4 v = *(const float4*)(in + (size_t)i * 4);
    u16x4 o; o.x = f2bf(v.x); o.y = f2bf(v.y); o.z = f2bf(v.z); o.w = f2bf(v.w);
    *(u16x4*)(out + (size_t)i * 4) = o;
  }
}

// ---------------- projection GEMM: C = A(M,K) @ W(N,K)^T, bf16, 128x128 tile ----------------
// which==0: q -> (b,h,s,c); which==1: k -> (b,h,s,c); which==2: v -> V^T (b,h,c,s)
__global__ __launch_bounds__(256) void gemm_proj_k(
    const unsigned short* __restrict__ qln, const unsigned short* __restrict__ kvln,
    const unsigned short* __restrict__ Wq,  const unsigned short* __restrict__ Wk,
    const unsigned short* __restrict__ Wv,
    unsigned short* __restrict__ qb, unsigned short* __restrict__ kb,
    unsigned short* __restrict__ vtb) {
  const int K = D_;
  int which = blockIdx.z;
  const unsigned short* A = (which == 0) ? qln : kvln;
  const unsigned short* W = (which == 0) ? Wq : (which == 1 ? Wk : Wv);
  unsigned short* O = (which == 0) ? qb : (which == 1 ? kb : vtb);
  int m0 = blockIdx.y * 128, n0 = blockIdx.x * 128;
  __shared__ unsigned short lsA[128 * 64];   // rows 128B, XOR-swizzled
  __shared__ unsigned short lsB[128 * 64];
  int tid = threadIdx.x, l = tid & 63, w = tid >> 6;
  int wm = (w >> 1) * 64, wn = (w & 1) * 64;
  f32x4 acc[4][4] = {};
  for (int kt = 0; kt < K; kt += 64) {
    __syncthreads();
#pragma unroll
    for (int i = 0; i < 4; i++) {                    // stage 128x64 A and B tiles
      int u = i * 256 + tid;
      int row = u >> 3, c16 = u & 7;
      int sw = ((c16 * 16) ^ ((row & 7) << 4));
      u16x8 av = *(const u16x8*)(A + (size_t)(m0 + row) * K + kt + c16 * 8);
      *(u16x8*)((char*)lsA + row * 128 + sw) = av;
      u16x8 bv = *(const u16x8*)(W + (size_t)(n0 + row) * K + kt + c16 * 8);
      *(u16x8*)((char*)lsB + row * 128 + sw) = bv;
    }
    __syncthreads();
#pragma unroll
    for (int kk = 0; kk < 2; kk++) {
      bf16x8 af[4], bfr[4];
      int koff = kk * 64 + (l >> 4) * 16;
#pragma unroll
      for (int mf = 0; mf < 4; mf++) {
        int row = wm + mf * 16 + (l & 15);
        af[mf] = *(const bf16x8*)((char*)lsA + row * 128 + (koff ^ ((row & 7) << 4)));
      }
#pragma unroll
      for (int nf = 0; nf < 4; nf++) {
        int row = wn + nf * 16 + (l & 15);
        bfr[nf] = *(const bf16x8*)((char*)lsB + row * 128 + (koff ^ ((row & 7) << 4)));
      }
#pragma unroll
      for (int mf = 0; mf < 4; mf++)
#pragma unroll
        for (int nf = 0; nf < 4; nf++)
          acc[mf][nf] = __builtin_amdgcn_mfma_f32_16x16x32_bf16(af[mf], bfr[nf], acc[mf][nf], 0, 0, 0);
    }
  }
  // epilogue: C/D layout col=lane&15, row=(lane>>4)*4+reg (m89-verified)
  if (which < 2) {
#pragma unroll
    for (int mf = 0; mf < 4; mf++)
#pragma unroll
      for (int nf = 0; nf < 4; nf++)
#pragma unroll
        for (int r = 0; r < 4; r++) {
          int gm = m0 + wm + mf * 16 + (l >> 4) * 4 + r;
          int gn = n0 + wn + nf * 16 + (l & 15);
          int b = gm >> 10, s = gm & 1023;
          int h = gn >> 7,  c = gn & 127;
          O[((size_t)((b * H_ + h) * S_ + s)) * C2_ + c] = f2bf(acc[mf][nf][r]);
        }
  } else {
    // V^T (b,h,c,s): reg r -> consecutive s -> packed 8B stores
#pragma unroll
    for (int mf = 0; mf < 4; mf++)
#pragma unroll
      for (int nf = 0; nf < 4; nf++) {
        int gm = m0 + wm + mf * 16 + (l >> 4) * 4;   // s base (r adds 0..3)
        int gn = n0 + wn + nf * 16 + (l & 15);
        int b = gm >> 10, s = gm & 1023;
        int h = gn >> 7,  c = gn & 127;
        u16x4 pk;
        pk.x = f2bf(acc[mf][nf][0]); pk.y = f2bf(acc[mf][nf][1]);
        pk.z = f2bf(acc[mf][nf][2]); pk.w = f2bf(acc[mf][nf][3]);
        *(u16x4*)(O + ((size_t)((b * H_ + h) * C2_ + c)) * S_ + s) = pk;
      }
  }
}

// ---------------- output GEMM: out = A(4096,2048) @ Wo(1024,2048)^T + resid ----------------
__global__ __launch_bounds__(256) void gemm_out_k(
    const unsigned short* __restrict__ A, const unsigned short* __restrict__ W,
    const float* __restrict__ resid, float* __restrict__ out) {
  const int K = E_;
  int m0 = blockIdx.y * 128, n0 = blockIdx.x * 128;
  __shared__ unsigned short lsA[128 * 64];
  __shared__ unsigned short lsB[128 * 64];
  int tid = threadIdx.x, l = tid & 63, w = tid >> 6;
  int wm = (w >> 1) * 64, wn = (w & 1) * 64;
  f32x4 acc[4][4] = {};
  for (int kt = 0; kt < K; kt += 64) {
    __syncthreads();
#pragma unroll
    for (int i = 0; i < 4; i++) {
      int u = i * 256 + tid;
      int row = u >> 3, c16 = u & 7;
      int sw = ((c16 * 16) ^ ((row & 7) << 4));
      u16x8 av = *(const u16x8*)(A + (size_t)(m0 + row) * K + kt + c16 * 8);
      *(u16x8*)((char*)lsA + row * 128 + sw) = av;
      u16x8 bv = *(const u16x8*)(W + (size_t)(n0 + row) * K + kt + c16 * 8);
      *(u16x8*)((char*)lsB + row * 128 + sw) = bv;
    }
    __syncthreads();
#pragma unroll
    for (int kk = 0; kk < 2; kk++) {
      bf16x8 af[4], bfr[4];
      int koff = kk * 64 + (l >> 4) * 16;
#pragma unroll
      for (int mf = 0; mf < 4; mf++) {
        int row = wm + mf * 16 + (l & 15);
        af[mf] = *(const bf16x8*)((char*)lsA + row * 128 + (koff ^ ((row & 7) << 4)));
      }
#pragma unroll
      for (int nf = 0; nf < 4; nf++) {
        int row = wn + nf * 16 + (l & 15);
        bfr[nf] = *(const bf16x8*)((char*)lsB + row * 128 + (koff ^ ((row & 7) << 4)));
      }
#pragma unroll
      for (int mf = 0; mf < 4; mf++)
#pragma unroll
        for (int nf = 0; nf < 4; nf++)
          acc[mf][nf] = __builtin_amdgcn_mfma_f32_16x16x32_bf16(af[mf], bfr[nf], acc[mf][nf], 0, 0, 0);
    }
  }
#pragma unroll
  for (int mf = 0; mf < 4; mf++)
#pragma unroll
    for (int nf = 0; nf < 4; nf++)
#pragma unroll
      for (int r = 0; r < 4; r++) {
        int gm = m0 + wm + mf * 16 + (l >> 4) * 4 + r;
        int gn = n0 + wn + nf * 16 + (l & 15);
        size_t idx = (size_t)gm * D_ + gn;
        out[idx] = acc[mf][nf][r] + resid[idx];
      }
}

// ---------------- differential flash attention + head LN (v2) ----------------
// block = (bh, qt): 128 Q-rows; 4 waves x 32 q (mf=2); KV tiles of 64.
// V frags shared across both terms; row-sum via ones-MFMA; DPP max; defer-max.
__global__ __launch_bounds__(256, 2) void attn_k(
    const unsigned short* __restrict__ q, const unsigned short* __restrict__ k,
    const unsigned short* __restrict__ vt,
    const float* __restrict__ lq1, const float* __restrict__ lk1,
    const float* __restrict__ lq2, const float* __restrict__ lk2,
    const float* __restrict__ hng, const float* __restrict__ hnb,
    const float* __restrict__ lambda_init, const int* __restrict__ dis2,
    unsigned short* __restrict__ out) {
  int bh = blockIdx.x;   // 0..63  (x-major -> same head on same XCD)
  int qt = blockIdx.y;   // 0..7
  int tid = threadIdx.x, l = tid & 63, w = tid >> 6;
  int g = l >> 4, c = l & 15;
  __shared__ unsigned short lsK[64 * 128];    // [key][feat] 256B rows, swizzled
  __shared__ unsigned short lsVt[128 * 64];   // [feat][key] 128B rows, swizzled
  __shared__ unsigned short lsP[4][2][32 * 64]; // per wave, per term: [q32][t64] swizzled
  __shared__ float s_lam, s_osc;

  if (tid < 64) {                             // lambda scalar (wave 0)
    float a = lq1[l] * lk1[l];
    float cc = lq2[l] * lk2[l];
#pragma unroll
    for (int m = 32; m; m >>= 1) { a += __shfl_xor(a, m, 64); cc += __shfl_xor(cc, m, 64); }
    if (l == 0) {
      float li = lambda_init[0];
      float lam = __expf(a) - __expf(cc) + li;
      if (dis2[0] != 0) lam = 0.f;
      s_lam = lam;
      s_osc = 1.f - li;
    }
  }

  // Q fragments: qf[term][kk][mf]; A-frag row = c, k = g*8+j within (term,kk) chunk
  int qbase = qt * 128 + w * 32;
  bf16x8 qf[2][2][2];
#pragma unroll
  for (int t = 0; t < 2; t++)
#pragma unroll
    for (int kk = 0; kk < 2; kk++)
#pragma unroll
      for (int mf = 0; mf < 2; mf++) {
        int qrow = qbase + mf * 16 + c;
        qf[t][kk][mf] = *(const bf16x8*)(q + ((size_t)bh * S_ + qrow) * C2_ + t * 64 + kk * 32 + g * 8);
      }

  float mrun[2][2][4];
  f32x4 lones[2][2] = {};
  f32x4 o[2][2][8] = {};
#pragma unroll
  for (int t = 0; t < 2; t++)
#pragma unroll
    for (int mf = 0; mf < 2; mf++)
#pragma unroll
      for (int r = 0; r < 4; r++) mrun[t][mf][r] = -1e30f;

  bf16x8 onesf;
#pragma unroll
  for (int j = 0; j < 8; j++) onesf[j] = (short)0x3F80;   // bf16 1.0

  const float cscale = 0.125f * 1.44269504f;  // 1/sqrt(64) * log2(e): exp2 domain

  for (int t0 = 0; t0 < S_; t0 += 64) {
    __syncthreads();
    const unsigned short* kbase = k + ((size_t)bh * S_ + t0) * C2_;
#pragma unroll
    for (int i = 0; i < 4; i++) {              // stage K tile (64x128)
      int u = i * 256 + tid, row = u >> 4, c16 = u & 15;
      u16x8 kv8 = *(const u16x8*)(kbase + row * C2_ + c16 * 8);
      *(u16x8*)((char*)lsK + row * 256 + ((c16 * 16) ^ ((row & 7) << 4))) = kv8;
    }
    const unsigned short* vtb = vt + (size_t)bh * C2_ * S_ + t0;
#pragma unroll
    for (int i = 0; i < 4; i++) {              // stage V^T tile (128 feat x 64 key), vector writes
      int u = i * 256 + tid, row = u >> 3, c8 = u & 7;
      u16x8 v8 = *(const u16x8*)(vtb + (size_t)row * S_ + c8 * 8);
      *(u16x8*)((char*)lsVt + row * 128 + ((c8 * 16) ^ ((row & 7) << 4))) = v8;
    }
    __syncthreads();

#pragma unroll
    for (int term = 0; term < 2; term++) {
      f32x4 sf[2][4] = {};   // [mf][nf]
      __builtin_amdgcn_s_setprio(1);
#pragma unroll
      for (int nf = 0; nf < 4; nf++) {
        int kfrow = nf * 16 + c;
#pragma unroll
        for (int kk = 0; kk < 2; kk++) {
          bf16x8 kf = *(const bf16x8*)((char*)lsK + kfrow * 256 +
                        ((term * 128 + kk * 64 + g * 16) ^ ((kfrow & 7) << 4)));
#pragma unroll
          for (int mf = 0; mf < 2; mf++)
            sf[mf][nf] = __builtin_amdgcn_mfma_f32_16x16x32_bf16(qf[term][kk][mf], kf, sf[mf][nf], 0, 0, 0);
        }
      }
      __builtin_amdgcn_s_setprio(0);
      // row maxes (scaled/log2 domain) + defer-max decision
      float xg[2][4];
      float growth = -1e30f;
#pragma unroll
      for (int mf = 0; mf < 2; mf++)
#pragma unroll
        for (int r = 0; r < 4; r++) {
          float x = fmaxf(fmaxf(sf[mf][0][r], sf[mf][1][r]), fmaxf(sf[mf][2][r], sf[mf][3][r])) * cscale;
          x = red16_max(x);
          xg[mf][r] = x;
          growth = fmaxf(growth, x - mrun[term][mf][r]);
        }
      if (!__all(growth <= 11.0f)) {           // T13: rescale only on real max growth
#pragma unroll
        for (int mf = 0; mf < 2; mf++)
#pragma unroll
          for (int r = 0; r < 4; r++) {
            float mn = fmaxf(mrun[term][mf][r], xg[mf][r]);
            float alpha = exp2f(mrun[term][mf][r] - mn);
            mrun[term][mf][r] = mn;
            lones[term][mf][r] *= alpha;
#pragma unroll
            for (int nf2 = 0; nf2 < 8; nf2++) o[term][mf][nf2][r] *= alpha;
          }
      }
      // P = exp2(s*cscale - m) -> bf16 -> per-wave LDS (swizzled)
      char* pbase = (char*)&lsP[w][term][0];
#pragma unroll
      for (int mf = 0; mf < 2; mf++)
#pragma unroll
        for (int nf = 0; nf < 4; nf++)
#pragma unroll
          for (int r = 0; r < 4; r++) {
            float p = exp2f(sf[mf][nf][r] * cscale - mrun[term][mf][r]);
            int prow = mf * 16 + g * 4 + r;
            *(unsigned short*)(pbase + prow * 128 +
                (((c + nf * 16) * 2) ^ ((prow & 7) << 4))) = f2bf(p);
          }
    }

    // PV for both terms, V frags read ONCE
#pragma unroll
    for (int kk = 0; kk < 2; kk++) {
      bf16x8 pa[2][2];
#pragma unroll
      for (int term = 0; term < 2; term++)
#pragma unroll
        for (int mf = 0; mf < 2; mf++) {
          int parow = mf * 16 + c;
          pa[term][mf] = *(const bf16x8*)((char*)&lsP[w][term][0] + parow * 128 +
                           ((kk * 64 + g * 16) ^ ((parow & 7) << 4)));
        }
      __builtin_amdgcn_s_setprio(1);
#pragma unroll
      for (int term = 0; term < 2; term++)
#pragma unroll
        for (int mf = 0; mf < 2; mf++)
          lones[term][mf] = __builtin_amdgcn_mfma_f32_16x16x32_bf16(pa[term][mf], onesf, lones[term][mf], 0, 0, 0);
#pragma unroll
      for (int nf2 = 0; nf2 < 8; nf2++) {
        int vrow = nf2 * 16 + c;
        bf16x8 vf = *(const bf16x8*)((char*)lsVt + vrow * 128 +
                      ((kk * 64 + g * 16) ^ ((vrow & 7) << 4)));
#pragma unroll
        for (int term = 0; term < 2; term++)
#pragma unroll
          for (int mf = 0; mf < 2; mf++)
            o[term][mf][nf2] = __builtin_amdgcn_mfma_f32_16x16x32_bf16(pa[term][mf], vf, o[term][mf][nf2], 0, 0, 0);
      }
      __builtin_amdgcn_s_setprio(0);
    }
  }

  // epilogue: combine terms, head-LN over 128, scale, store bf16 (B,S,2048)
  float lam = s_lam, osc = s_osc;
  int b = bh >> 4, h = bh & 15;
#pragma unroll
  for (int mf = 0; mf < 2; mf++)
#pragma unroll
    for (int r = 0; r < 4; r++) {
      float inv1 = 1.f / lones[0][mf][r];
      float inv2 = lam / lones[1][mf][r];
      float vals[8];
      float sum = 0.f, sq = 0.f;
#pragma unroll
      for (int nf2 = 0; nf2 < 8; nf2++) {
        float vv = o[0][mf][nf2][r] * inv1 - o[1][mf][nf2][r] * inv2;
        vals[nf2] = vv;
        sum += vv; sq += vv * vv;
      }
      sum = red16_sum(sum);
      sq  = red16_sum(sq);
      float mean = sum * (1.f / 128.f);
      float var  = sq * (1.f / 128.f) - mean * mean;
      float rstd = rsqrtf(var + 1e-5f);
      int srow = qt * 128 + w * 32 + mf * 16 + g * 4 + r;
      unsigned short* orow = out + ((size_t)(b * S_ + srow)) * E_ + h * C2_;
#pragma unroll
      for (int nf2 = 0; nf2 < 8; nf2++) {
        int feat = nf2 * 16 + c;
        float y = (vals[nf2] - mean) * rstd * hng[feat] + hnb[feat];
        orow[feat] = f2bf(y * osc);
      }
    }
}

// ---------------- host launcher ----------------
extern "C" void kernel_launch(void* const* d_in, const int* in_sizes, int n_in,
                              void* d_out, int out_size, void* d_ws, size_t ws_size,
                              hipStream_t stream) {
  const float* qtok = (const float*)d_in[0];
  const float* kvtok = (const float*)d_in[1];
  const float* lnqg = (const float*)d_in[2];
  const float* lnqb = (const float*)d_in[3];
  const float* lnkg = (const float*)d_in[4];
  const float* lnkb = (const float*)d_in[5];
  const float* Wq = (const float*)d_in[6];
  const float* Wk = (const float*)d_in[7];
  const float* Wv = (const float*)d_in[8];
  const float* Wo = (const float*)d_in[9];
  const float* lq1 = (const float*)d_in[10];
  const float* lk1 = (const float*)d_in[11];
  const float* lq2 = (const float*)d_in[12];
  const float* lk2 = (const float*)d_in[13];
  const float* hng = (const float*)d_in[14];
  const float* hnb = (const float*)d_in[15];
  const float* lami = (const float*)d_in[16];
  const int*   dis2 = (const int*)d_in[17];
  float* outp = (float*)d_out;

  char* ws = (char*)d_ws;
  const size_t MB = 1024 * 1024;
  // layout (80 MB peak): [0,16) qln+kvln, later reused as attn_out; [16,32) bf16 weights;
  // [32,80) q/k (b,h,s,c) and V^T (b,h,c,s).
  unsigned short* qln    = (unsigned short*)(ws + 0);
  unsigned short* kvln   = (unsigned short*)(ws + 8 * MB);
  unsigned short* attn_o = (unsigned short*)(ws + 0);        // aliases qln/kvln (dead by then)
  unsigned short* Wqb = (unsigned short*)(ws + 16 * MB);
  unsigned short* Wkb = (unsigned short*)(ws + 20 * MB);
  unsigned short* Wvb = (unsigned short*)(ws + 24 * MB);
  unsigned short* Wob = (unsigned short*)(ws + 28 * MB);
  unsigned short* qb  = (unsigned short*)(ws + 32 * MB);
  unsigned short* kb  = (unsigned short*)(ws + 48 * MB);
  unsigned short* vtb = (unsigned short*)(ws + 64 * MB);

  ln_cast_k<<<dim3(4096), dim3(256), 0, stream>>>(qtok, lnqg, lnqb, qln);
  ln_cast_k<<<dim3(4096), dim3(256), 0, stream>>>(kvtok, lnkg, lnkb, kvln);
  cast_k<<<dim3(2048), dim3(256), 0, stream>>>(Wq, Wqb, 512 * 1024);
  cast_k<<<dim3(2048), dim3(256), 0, stream>>>(Wk, Wkb, 512 * 1024);
  cast_k<<<dim3(2048), dim3(256), 0, stream>>>(Wv, Wvb, 512 * 1024);
  cast_k<<<dim3(2048), dim3(256), 0, stream>>>(Wo, Wob, 512 * 1024);
  gemm_proj_k<<<dim3(16, 32, 3), dim3(256), 0, stream>>>(qln, kvln, Wqb, Wkb, Wvb, qb, kb, vtb);
  attn_k<<<dim3(64, 8), dim3(256), 0, stream>>>(qb, kb, vtb, lq1, lk1, lq2, lk2,
                                                hng, hnb, lami, dis2, attn_o);
  gemm_out_k<<<dim3(8, 32), dim3(256), 0, stream>>>(attn_o, Wob, qtok, outp);
}

// Round 3
// 245.128 us; speedup vs baseline: 1.7632x; 1.7632x over previous
//
#include <hip/hip_runtime.h>
#include <stdint.h>

#define B_  4
#define S_  1024
#define D_  1024
#define H_  16
#define HD_ 64
#define E_  2048   // 2*D
#define C2_ 128    // 2*HD

typedef __attribute__((ext_vector_type(8))) short          bf16x8;  // MFMA A/B frag (8 bf16)
typedef __attribute__((ext_vector_type(8))) unsigned short u16x8;
typedef __attribute__((ext_vector_type(4))) unsigned short u16x4;
typedef __attribute__((ext_vector_type(4))) float          f32x4;   // MFMA C/D frag

__device__ __forceinline__ unsigned short f2bf(float f) {
  union { float f; unsigned int u; } v; v.f = f;
  unsigned int r = v.u + 0x7fffu + ((v.u >> 16) & 1u);   // RNE
  return (unsigned short)(r >> 16);
}

__device__ __forceinline__ unsigned int cvtpk_bf16(float lo, float hi) {
  unsigned int r;
  asm("v_cvt_pk_bf16_f32 %0, %1, %2" : "=v"(r) : "v"(lo), "v"(hi));
  return r;
}

// 16-lane (DPP row) sum — VALU only.
__device__ __forceinline__ float red16_sum(float x) {
  x += __int_as_float(__builtin_amdgcn_mov_dpp(__float_as_int(x), 0xB1, 0xF, 0xF, false));
  x += __int_as_float(__builtin_amdgcn_mov_dpp(__float_as_int(x), 0x4E, 0xF, 0xF, false));
  x += __int_as_float(__builtin_amdgcn_mov_dpp(__float_as_int(x), 0x141, 0xF, 0xF, false));
  x += __int_as_float(__builtin_amdgcn_mov_dpp(__float_as_int(x), 0x140, 0xF, 0xF, false));
  return x;
}

// ---------------- LayerNorm (D=1024) + bf16 cast ----------------
__global__ __launch_bounds__(256) void ln_cast_k(const float* __restrict__ x,
                                                 const float* __restrict__ g,
                                                 const float* __restrict__ bb,
                                                 unsigned short* __restrict__ out) {
  int row = blockIdx.x;
  int tid = threadIdx.x;
  const float* xr = x + (size_t)row * D_;
  float4 xv = *(const float4*)(xr + tid * 4);
  float s  = xv.x + xv.y + xv.z + xv.w;
  float sq = xv.x * xv.x + xv.y * xv.y + xv.z * xv.z + xv.w * xv.w;
#pragma unroll
  for (int m = 32; m; m >>= 1) { s += __shfl_xor(s, m, 64); sq += __shfl_xor(sq, m, 64); }
  __shared__ float ps[4], pq[4];
  int w = tid >> 6, l = tid & 63;
  if (l == 0) { ps[w] = s; pq[w] = sq; }
  __syncthreads();
  s  = ps[0] + ps[1] + ps[2] + ps[3];
  sq = pq[0] + pq[1] + pq[2] + pq[3];
  float mean = s * (1.f / D_);
  float var  = sq * (1.f / D_) - mean * mean;
  float rstd = rsqrtf(var + 1e-5f);
  float4 gv = *(const float4*)(g + tid * 4);
  float4 bv = *(const float4*)(bb + tid * 4);
  u16x4 o;
  o.x = f2bf((xv.x - mean) * rstd * gv.x + bv.x);
  o.y = f2bf((xv.y - mean) * rstd * gv.y + bv.y);
  o.z = f2bf((xv.z - mean) * rstd * gv.z + bv.z);
  o.w = f2bf((xv.w - mean) * rstd * gv.w + bv.w);
  *(u16x4*)(out + (size_t)row * D_ + tid * 4) = o;
}

// ---------------- fp32 -> bf16 cast (weights) ----------------
__global__ __launch_bounds__(256) void cast_k(const float* __restrict__ in,
                                              unsigned short* __restrict__ out, int n4) {
  int i = blockIdx.x * 256 + threadIdx.x;
  if (i < n4) {
    float4 v = *(const float4*)(in + (size_t)i * 4);
    u16x4 o; o.x = f2bf(v.x); o.y = f2bf(v.y); o.z = f2bf(v.z); o.w = f2bf(v.w);
    *(u16x4*)(out + (size_t)i * 4) = o;
  }
}

// ---------------- projection GEMM: C = A(M,K) @ W(N,K)^T, bf16, 128x128 tile ----------------
// which==0: q -> (b,h,s,c); which==1: k -> (b,h,s,c); which==2: v -> V^T (b,h,c,s) via LDS transpose
__global__ __launch_bounds__(256) void gemm_proj_k(
    const unsigned short* __restrict__ qln, const unsigned short* __restrict__ kvln,
    const unsigned short* __restrict__ Wq,  const unsigned short* __restrict__ Wk,
    const unsigned short* __restrict__ Wv,
    unsigned short* __restrict__ qb, unsigned short* __restrict__ kb,
    unsigned short* __restrict__ vtb) {
  const int K = D_;
  int which = blockIdx.z;
  const unsigned short* A = (which == 0) ? qln : kvln;
  const unsigned short* W = (which == 0) ? Wq : (which == 1 ? Wk : Wv);
  unsigned short* O = (which == 0) ? qb : (which == 1 ? kb : vtb);
  int m0 = blockIdx.y * 128, n0 = blockIdx.x * 128;
  __shared__ __align__(16) char psm[128 * 272];   // aliases: lsA(16K) + lsB(16K) | lsT(34816)
  char* lsA = psm;
  char* lsB = psm + 16384;
  int tid = threadIdx.x, l = tid & 63, w = tid >> 6;
  int wm = (w >> 1) * 64, wn = (w & 1) * 64;
  f32x4 acc[4][4] = {};
  for (int kt = 0; kt < K; kt += 64) {
    __syncthreads();
#pragma unroll
    for (int i = 0; i < 4; i++) {                    // stage 128x64 A and B tiles
      int u = i * 256 + tid;
      int row = u >> 3, c16 = u & 7;
      int sw = ((c16 * 16) ^ ((row & 7) << 4));
      u16x8 av = *(const u16x8*)(A + (size_t)(m0 + row) * K + kt + c16 * 8);
      *(u16x8*)(lsA + row * 128 + sw) = av;
      u16x8 bv = *(const u16x8*)(W + (size_t)(n0 + row) * K + kt + c16 * 8);
      *(u16x8*)(lsB + row * 128 + sw) = bv;
    }
    __syncthreads();
#pragma unroll
    for (int kk = 0; kk < 2; kk++) {
      bf16x8 af[4], bfr[4];
      int koff = kk * 64 + (l >> 4) * 16;
#pragma unroll
      for (int mf = 0; mf < 4; mf++) {
        int row = wm + mf * 16 + (l & 15);
        af[mf] = *(const bf16x8*)(lsA + row * 128 + (koff ^ ((row & 7) << 4)));
      }
#pragma unroll
      for (int nf = 0; nf < 4; nf++) {
        int row = wn + nf * 16 + (l & 15);
        bfr[nf] = *(const bf16x8*)(lsB + row * 128 + (koff ^ ((row & 7) << 4)));
      }
#pragma unroll
      for (int mf = 0; mf < 4; mf++)
#pragma unroll
        for (int nf = 0; nf < 4; nf++)
          acc[mf][nf] = __builtin_amdgcn_mfma_f32_16x16x32_bf16(af[mf], bfr[nf], acc[mf][nf], 0, 0, 0);
    }
  }
  // epilogue: C/D layout col=lane&15, row=(lane>>4)*4+reg (m89-verified)
  if (which < 2) {
#pragma unroll
    for (int mf = 0; mf < 4; mf++)
#pragma unroll
      for (int nf = 0; nf < 4; nf++)
#pragma unroll
        for (int r = 0; r < 4; r++) {
          int gm = m0 + wm + mf * 16 + (l >> 4) * 4 + r;
          int gn = n0 + wn + nf * 16 + (l & 15);
          int b = gm >> 10, s = gm & 1023;
          int h = gn >> 7,  c = gn & 127;
          O[((size_t)((b * H_ + h) * S_ + s)) * C2_ + c] = f2bf(acc[mf][nf][r]);
        }
  } else {
    // V^T: write bf16 tile to LDS [feat 128][s 128] (272B stride), read back rows, store coalesced
    __syncthreads();
#pragma unroll
    for (int mf = 0; mf < 4; mf++)
#pragma unroll
      for (int nf = 0; nf < 4; nf++) {
        int crow = wn + nf * 16 + (l & 15);          // tile-local feature
        int sloc = wm + mf * 16 + (l >> 4) * 4;      // tile-local s (r packs 0..3)
        u16x4 pk4;
        pk4.x = f2bf(acc[mf][nf][0]); pk4.y = f2bf(acc[mf][nf][1]);
        pk4.z = f2bf(acc[mf][nf][2]); pk4.w = f2bf(acc[mf][nf][3]);
        *(u16x4*)(psm + (size_t)crow * 272 + sloc * 2) = pk4;
      }
    __syncthreads();
    int b = m0 >> 10, sbase = m0 & 1023;
#pragma unroll
    for (int i = 0; i < 8; i++) {
      int u2 = i * 256 + tid;
      int row = u2 >> 4, c16 = u2 & 15;
      u16x8 vv = *(const u16x8*)(psm + (size_t)row * 272 + c16 * 16);
      int gn = n0 + row, h = gn >> 7, cfeat = gn & 127;
      *(u16x8*)(O + ((size_t)((b * H_ + h) * C2_ + cfeat)) * S_ + sbase + c16 * 8) = vv;
    }
  }
}

// ---------------- output GEMM: out = A(4096,2048) @ Wo(1024,2048)^T + resid ----------------
__global__ __launch_bounds__(256) void gemm_out_k(
    const unsigned short* __restrict__ A, const unsigned short* __restrict__ W,
    const float* __restrict__ resid, float* __restrict__ out) {
  const int K = E_;
  int m0 = blockIdx.y * 128, n0 = blockIdx.x * 128;
  __shared__ unsigned short lsA[128 * 64];
  __shared__ unsigned short lsB[128 * 64];
  int tid = threadIdx.x, l = tid & 63, w = tid >> 6;
  int wm = (w >> 1) * 64, wn = (w & 1) * 64;
  f32x4 acc[4][4] = {};
  for (int kt = 0; kt < K; kt += 64) {
    __syncthreads();
#pragma unroll
    for (int i = 0; i < 4; i++) {
      int u = i * 256 + tid;
      int row = u >> 3, c16 = u & 7;
      int sw = ((c16 * 16) ^ ((row & 7) << 4));
      u16x8 av = *(const u16x8*)(A + (size_t)(m0 + row) * K + kt + c16 * 8);
      *(u16x8*)((char*)lsA + row * 128 + sw) = av;
      u16x8 bv = *(const u16x8*)(W + (size_t)(n0 + row) * K + kt + c16 * 8);
      *(u16x8*)((char*)lsB + row * 128 + sw) = bv;
    }
    __syncthreads();
#pragma unroll
    for (int kk = 0; kk < 2; kk++) {
      bf16x8 af[4], bfr[4];
      int koff = kk * 64 + (l >> 4) * 16;
#pragma unroll
      for (int mf = 0; mf < 4; mf++) {
        int row = wm + mf * 16 + (l & 15);
        af[mf] = *(const bf16x8*)((char*)lsA + row * 128 + (koff ^ ((row & 7) << 4)));
      }
#pragma unroll
      for (int nf = 0; nf < 4; nf++) {
        int row = wn + nf * 16 + (l & 15);
        bfr[nf] = *(const bf16x8*)((char*)lsB + row * 128 + (koff ^ ((row & 7) << 4)));
      }
#pragma unroll
      for (int mf = 0; mf < 4; mf++)
#pragma unroll
        for (int nf = 0; nf < 4; nf++)
          acc[mf][nf] = __builtin_amdgcn_mfma_f32_16x16x32_bf16(af[mf], bfr[nf], acc[mf][nf], 0, 0, 0);
    }
  }
#pragma unroll
  for (int mf = 0; mf < 4; mf++)
#pragma unroll
    for (int nf = 0; nf < 4; nf++)
#pragma unroll
      for (int r = 0; r < 4; r++) {
        int gm = m0 + wm + mf * 16 + (l >> 4) * 4 + r;
        int gn = n0 + wn + nf * 16 + (l & 15);
        size_t idx = (size_t)gm * D_ + gn;
        out[idx] = acc[mf][nf][r] + resid[idx];
      }
}

// ---------------- differential flash attention + head LN (v3: swapped QK^T, in-reg P) ----------------
// block = (qt, bh): 64 Q-rows; 4 waves x 16 q. Per tile (64 keys):
//   S^T = mfma(K, Q): lane(g,c) holds S^T[key=nf*16+g*4+r][q=c] -> softmax lane-local.
//   P -> bf16 A-frags in-register via cvt_pk + permlane32_swap + shfl16-select.
//   PV: mfma(P, V): V frags read once, shared across both terms.
__global__ __launch_bounds__(256) void attn_k(
    const unsigned short* __restrict__ q, const unsigned short* __restrict__ k,
    const unsigned short* __restrict__ vt,
    const float* __restrict__ lq1, const float* __restrict__ lk1,
    const float* __restrict__ lq2, const float* __restrict__ lk2,
    const float* __restrict__ hng, const float* __restrict__ hnb,
    const float* __restrict__ lambda_init, const int* __restrict__ dis2,
    unsigned short* __restrict__ out) {
  int qt = blockIdx.x;   // 0..15 (x-major: consecutive blocks share bh -> L2 locality)
  int bh = blockIdx.y;   // 0..63
  int tid = threadIdx.x, ln = tid & 63, w = tid >> 6;
  int g = ln >> 4, c = ln & 15;
  bool godd = (g & 1);
  __shared__ unsigned short lsK[64 * 128];    // [key][feat] 256B rows, swizzled
  __shared__ unsigned short lsVt[128 * 64];   // [feat][key] 128B rows, swizzled
  __shared__ float s_lam, s_osc;

  if (tid < 64) {                             // lambda scalar (wave 0)
    float a = lq1[ln] * lk1[ln];
    float cc = lq2[ln] * lk2[ln];
#pragma unroll
    for (int m = 32; m; m >>= 1) { a += __shfl_xor(a, m, 64); cc += __shfl_xor(cc, m, 64); }
    if (ln == 0) {
      float li = lambda_init[0];
      float lam = __expf(a) - __expf(cc) + li;
      if (dis2[0] != 0) lam = 0.f;
      s_lam = lam;
      s_osc = 1.f - li;
    }
  }

  // Q as B-frags: col=lane&15 -> q-row, k=g*8+j -> feature
  int qrow = qt * 64 + w * 16 + c;
  const unsigned short* qrp = q + ((size_t)bh * S_ + qrow) * C2_;
  bf16x8 qf[2][2];
#pragma unroll
  for (int t = 0; t < 2; t++)
#pragma unroll
    for (int kk = 0; kk < 2; kk++)
      qf[t][kk] = *(const bf16x8*)(qrp + t * 64 + kk * 32 + g * 8);

  float mrun[2], lrun[2];
  mrun[0] = mrun[1] = -1e30f;
  lrun[0] = lrun[1] = 0.f;
  f32x4 o[2][8] = {};

  const float cscale = 0.125f * 1.44269504f;  // 1/sqrt(64) * log2(e)

  for (int t0 = 0; t0 < S_; t0 += 64) {
    __syncthreads();
    const unsigned short* kbase = k + ((size_t)bh * S_ + t0) * C2_;
#pragma unroll
    for (int i = 0; i < 4; i++) {              // stage K tile (64 keys x 128 feat)
      int u = i * 256 + tid, row = u >> 4, c16 = u & 15;
      u16x8 kv8 = *(const u16x8*)(kbase + row * C2_ + c16 * 8);
      *(u16x8*)((char*)lsK + row * 256 + ((c16 * 16) ^ ((row & 7) << 4))) = kv8;
    }
    const unsigned short* vtbp = vt + (size_t)bh * C2_ * S_ + t0;
#pragma unroll
    for (int i = 0; i < 4; i++) {              // stage V^T tile (128 feat x 64 key)
      int u = i * 256 + tid, row = u >> 3, c8 = u & 7;
      u16x8 v8 = *(const u16x8*)(vtbp + (size_t)row * S_ + c8 * 8);
      *(u16x8*)((char*)lsVt + row * 128 + ((c8 * 16) ^ ((row & 7) << 4))) = v8;
    }
    __syncthreads();

    unsigned int paw[2][2][4];                 // [term][kk][word] P A-frags

#pragma unroll
    for (int term = 0; term < 2; term++) {
      f32x4 sf[4] = {};                        // sf[nf]: keys nf*16+g*4+r, q=c
      __builtin_amdgcn_s_setprio(1);
#pragma unroll
      for (int kk = 0; kk < 2; kk++) {
#pragma unroll
        for (int nf = 0; nf < 4; nf++) {
          int kfrow = nf * 16 + c;
          bf16x8 kf = *(const bf16x8*)((char*)lsK + kfrow * 256 +
                        ((term * 128 + kk * 64 + g * 16) ^ ((kfrow & 7) << 4)));
          sf[nf] = __builtin_amdgcn_mfma_f32_16x16x32_bf16(kf, qf[term][kk], sf[nf], 0, 0, 0);
        }
      }
      __builtin_amdgcn_s_setprio(0);
      // tile max over 64 keys for q=c: 15 in-lane + 2 cross-g shuffles
      float mx = fmaxf(fmaxf(fmaxf(sf[0][0], sf[0][1]), fmaxf(sf[0][2], sf[0][3])),
                       fmaxf(fmaxf(sf[1][0], sf[1][1]), fmaxf(sf[1][2], sf[1][3])));
      mx = fmaxf(mx, fmaxf(fmaxf(fmaxf(sf[2][0], sf[2][1]), fmaxf(sf[2][2], sf[2][3])),
                           fmaxf(fmaxf(sf[3][0], sf[3][1]), fmaxf(sf[3][2], sf[3][3]))));
      mx *= cscale;
      mx = fmaxf(mx, __shfl_xor(mx, 16));
      mx = fmaxf(mx, __shfl_xor(mx, 32));
      if (!__all(mx - mrun[term] <= 11.0f)) {  // T13 defer-max (log2 domain)
        float mn = fmaxf(mrun[term], mx);
        float alpha = exp2f(mrun[term] - mn);
        mrun[term] = mn;
        lrun[term] *= alpha;
        int srcb = (ln & 48) | (g << 2);
#pragma unroll
        for (int r = 0; r < 4; r++) {
          float aO = __shfl(alpha, srcb | r);  // alpha for q=g*4+r
#pragma unroll
          for (int nf2 = 0; nf2 < 8; nf2++) o[term][nf2][r] *= aO;
        }
      }
      float lsum = 0.f;
#pragma unroll
      for (int nf = 0; nf < 4; nf++)
#pragma unroll
        for (int r = 0; r < 4; r++) {
          float p = exp2f(sf[nf][r] * cscale - mrun[term]);
          sf[nf][r] = p;
          lsum += p;
        }
      lsum += __shfl_xor(lsum, 16);
      lsum += __shfl_xor(lsum, 32);
      lrun[term] += lsum;
      // pack P to bf16 A-frags: chunk kk uses sf[2kk], sf[2kk+1]
#pragma unroll
      for (int kk = 0; kk < 2; kk++) {
        unsigned int X0 = cvtpk_bf16(sf[2 * kk][0], sf[2 * kk][1]);
        unsigned int X1 = cvtpk_bf16(sf[2 * kk][2], sf[2 * kk][3]);
        unsigned int Y0 = cvtpk_bf16(sf[2 * kk + 1][0], sf[2 * kk + 1][1]);
        unsigned int Y1 = cvtpk_bf16(sf[2 * kk + 1][2], sf[2 * kk + 1][3]);
        asm("v_permlane32_swap_b32 %0, %1" : "+v"(X0), "+v"(Y0));   // g01 <-> g23 halves
        asm("v_permlane32_swap_b32 %0, %1" : "+v"(X1), "+v"(Y1));
        {                                                           // 16-swap via shfl+select
          unsigned int t0w = __shfl_xor((int)Y0, 16), u0 = __shfl_xor((int)X0, 16);
          unsigned int t1w = __shfl_xor((int)Y1, 16), u1 = __shfl_xor((int)X1, 16);
          unsigned int nX0 = godd ? t0w : X0, nY0 = godd ? Y0 : u0;
          unsigned int nX1 = godd ? t1w : X1, nY1 = godd ? Y1 : u1;
          paw[term][kk][0] = nX0; paw[term][kk][1] = nX1;
          paw[term][kk][2] = nY0; paw[term][kk][3] = nY1;
        }
      }
    }

    // PV both terms, V frags read ONCE
#pragma unroll
    for (int kk = 0; kk < 2; kk++) {
      union { unsigned int u[4]; bf16x8 v; } pa0, pa1;
#pragma unroll
      for (int j = 0; j < 4; j++) { pa0.u[j] = paw[0][kk][j]; pa1.u[j] = paw[1][kk][j]; }
      __builtin_amdgcn_s_setprio(1);
#pragma unroll
      for (int nf2 = 0; nf2 < 8; nf2++) {
        int vrow = nf2 * 16 + c;
        bf16x8 vf = *(const bf16x8*)((char*)lsVt + vrow * 128 +
                      ((kk * 64 + g * 16) ^ ((vrow & 7) << 4)));
        o[0][nf2] = __builtin_amdgcn_mfma_f32_16x16x32_bf16(pa0.v, vf, o[0][nf2], 0, 0, 0);
        o[1][nf2] = __builtin_amdgcn_mfma_f32_16x16x32_bf16(pa1.v, vf, o[1][nf2], 0, 0, 0);
      }
      __builtin_amdgcn_s_setprio(0);
    }
  }

  // epilogue: redistribute 1/l to O-layout, combine, head-LN over 128, store
  float lam = s_lam, osc = s_osc;
  float rl1 = 1.f / lrun[0];
  float rl2 = lam / lrun[1];
  int srcb = (ln & 48) | (g << 2);
  int b = bh >> 4, h = bh & 15;
#pragma unroll
  for (int r = 0; r < 4; r++) {
    float inv1 = __shfl(rl1, srcb | r);
    float inv2 = __shfl(rl2, srcb | r);
    float vals[8];
    float sum = 0.f, sq = 0.f;
#pragma unroll
    for (int nf2 = 0; nf2 < 8; nf2++) {
      float vv = o[0][nf2][r] * inv1 - o[1][nf2][r] * inv2;
      vals[nf2] = vv;
      sum += vv; sq += vv * vv;
    }
    sum = red16_sum(sum);
    sq  = red16_sum(sq);
    float mean = sum * (1.f / 128.f);
    float var  = sq * (1.f / 128.f) - mean * mean;
    float rstd = rsqrtf(var + 1e-5f);
    int srow = qt * 64 + w * 16 + g * 4 + r;
    unsigned short* orow = out + ((size_t)(b * S_ + srow)) * E_ + h * C2_;
#pragma unroll
    for (int nf2 = 0; nf2 < 8; nf2++) {
      int feat = nf2 * 16 + c;
      float y = (vals[nf2] - mean) * rstd * hng[feat] + hnb[feat];
      orow[feat] = f2bf(y * osc);
    }
  }
}

// ---------------- host launcher ----------------
extern "C" void kernel_launch(void* const* d_in, const int* in_sizes, int n_in,
                              void* d_out, int out_size, void* d_ws, size_t ws_size,
                              hipStream_t stream) {
  const float* qtok = (const float*)d_in[0];
  const float* kvtok = (const float*)d_in[1];
  const float* lnqg = (const float*)d_in[2];
  const float* lnqb = (const float*)d_in[3];
  const float* lnkg = (const float*)d_in[4];
  const float* lnkb = (const float*)d_in[5];
  const float* Wq = (const float*)d_in[6];
  const float* Wk = (const float*)d_in[7];
  const float* Wv = (const float*)d_in[8];
  const float* Wo = (const float*)d_in[9];
  const float* lq1 = (const float*)d_in[10];
  const float* lk1 = (const float*)d_in[11];
  const float* lq2 = (const float*)d_in[12];
  const float* lk2 = (const float*)d_in[13];
  const float* hng = (const float*)d_in[14];
  const float* hnb = (const float*)d_in[15];
  const float* lami = (const float*)d_in[16];
  const int*   dis2 = (const int*)d_in[17];
  float* outp = (float*)d_out;

  char* ws = (char*)d_ws;
  const size_t MB = 1024 * 1024;
  unsigned short* qln    = (unsigned short*)(ws + 0);
  unsigned short* kvln   = (unsigned short*)(ws + 8 * MB);
  unsigned short* attn_o = (unsigned short*)(ws + 0);        // aliases qln/kvln (dead by then)
  unsigned short* Wqb = (unsigned short*)(ws + 16 * MB);
  unsigned short* Wkb = (unsigned short*)(ws + 20 * MB);
  unsigned short* Wvb = (unsigned short*)(ws + 24 * MB);
  unsigned short* Wob = (unsigned short*)(ws + 28 * MB);
  unsigned short* qb  = (unsigned short*)(ws + 32 * MB);
  unsigned short* kb  = (unsigned short*)(ws + 48 * MB);
  unsigned short* vtb = (unsigned short*)(ws + 64 * MB);

  ln_cast_k<<<dim3(4096), dim3(256), 0, stream>>>(qtok, lnqg, lnqb, qln);
  ln_cast_k<<<dim3(4096), dim3(256), 0, stream>>>(kvtok, lnkg, lnkb, kvln);
  cast_k<<<dim3(2048), dim3(256), 0, stream>>>(Wq, Wqb, 512 * 1024);
  cast_k<<<dim3(2048), dim3(256), 0, stream>>>(Wk, Wkb, 512 * 1024);
  cast_k<<<dim3(2048), dim3(256), 0, stream>>>(Wv, Wvb, 512 * 1024);
  cast_k<<<dim3(2048), dim3(256), 0, stream>>>(Wo, Wob, 512 * 1024);
  gemm_proj_k<<<dim3(16, 32, 3), dim3(256), 0, stream>>>(qln, kvln, Wqb, Wkb, Wvb, qb, kb, vtb);
  attn_k<<<dim3(16, 64), dim3(256), 0, stream>>>(qb, kb, vtb, lq1, lk1, lq2, lk2,
                                                 hng, hnb, lami, dis2, attn_o);
  gemm_out_k<<<dim3(8, 32), dim3(256), 0, stream>>>(attn_o, Wob, qtok, outp);
}

// Round 5
// 217.714 us; speedup vs baseline: 1.9853x; 1.1259x over previous
//
#include <hip/hip_runtime.h>
#include <stdint.h>

#define B_  4
#define S_  1024
#define D_  1024
#define H_  16
#define HD_ 64
#define E_  2048   // 2*D
#define C2_ 128    // 2*HD

typedef __attribute__((ext_vector_type(8))) short          bf16x8;  // MFMA A/B frag (8 bf16)
typedef __attribute__((ext_vector_type(8))) unsigned short u16x8;
typedef __attribute__((ext_vector_type(4))) unsigned short u16x4;
typedef __attribute__((ext_vector_type(4))) float          f32x4;   // MFMA C/D frag

#define QSCALE 0.18033688f   // (1/sqrt(HD)) * log2(e) — folded into Q at projection

__device__ __forceinline__ unsigned short f2bf(float f) {
  union { float f; unsigned int u; } v; v.f = f;
  unsigned int r = v.u + 0x7fffu + ((v.u >> 16) & 1u);   // RNE
  return (unsigned short)(r >> 16);
}

__device__ __forceinline__ unsigned int cvtpk_bf16(float lo, float hi) {
  unsigned int r;
  asm("v_cvt_pk_bf16_f32 %0, %1, %2" : "=v"(r) : "v"(lo), "v"(hi));
  return r;
}

// 16-lane (DPP row) sum — VALU only.
__device__ __forceinline__ float red16_sum(float x) {
  x += __int_as_float(__builtin_amdgcn_mov_dpp(__float_as_int(x), 0xB1, 0xF, 0xF, false));
  x += __int_as_float(__builtin_amdgcn_mov_dpp(__float_as_int(x), 0x4E, 0xF, 0xF, false));
  x += __int_as_float(__builtin_amdgcn_mov_dpp(__float_as_int(x), 0x141, 0xF, 0xF, false));
  x += __int_as_float(__builtin_amdgcn_mov_dpp(__float_as_int(x), 0x140, 0xF, 0xF, false));
  return x;
}

// async global -> LDS, 16B per lane. LDS dest = uniform base + lane*16 (HW rule).
typedef const __attribute__((address_space(1))) unsigned int* gas1_t;
typedef __attribute__((address_space(3))) unsigned int* las3_t;
__device__ __forceinline__ void gload16(const void* g, void* s) {
  __builtin_amdgcn_global_load_lds((gas1_t)g, (las3_t)s, 16, 0, 0);
}

// ---------------- LayerNorm (D=1024) + bf16 cast ----------------
__global__ __launch_bounds__(256) void ln_cast_k(const float* __restrict__ x,
                                                 const float* __restrict__ g,
                                                 const float* __restrict__ bb,
                                                 unsigned short* __restrict__ out) {
  int row = blockIdx.x;
  int tid = threadIdx.x;
  const float* xr = x + (size_t)row * D_;
  float4 xv = *(const float4*)(xr + tid * 4);
  float s  = xv.x + xv.y + xv.z + xv.w;
  float sq = xv.x * xv.x + xv.y * xv.y + xv.z * xv.z + xv.w * xv.w;
#pragma unroll
  for (int m = 32; m; m >>= 1) { s += __shfl_xor(s, m, 64); sq += __shfl_xor(sq, m, 64); }
  __shared__ float ps[4], pq[4];
  int w = tid >> 6, l = tid & 63;
  if (l == 0) { ps[w] = s; pq[w] = sq; }
  __syncthreads();
  s  = ps[0] + ps[1] + ps[2] + ps[3];
  sq = pq[0] + pq[1] + pq[2] + pq[3];
  float mean = s * (1.f / D_);
  float var  = sq * (1.f / D_) - mean * mean;
  float rstd = rsqrtf(var + 1e-5f);
  float4 gv = *(const float4*)(g + tid * 4);
  float4 bv = *(const float4*)(bb + tid * 4);
  u16x4 o;
  o.x = f2bf((xv.x - mean) * rstd * gv.x + bv.x);
  o.y = f2bf((xv.y - mean) * rstd * gv.y + bv.y);
  o.z = f2bf((xv.z - mean) * rstd * gv.z + bv.z);
  o.w = f2bf((xv.w - mean) * rstd * gv.w + bv.w);
  *(u16x4*)(out + (size_t)row * D_ + tid * 4) = o;
}

// ---------------- fp32 -> bf16 cast (weights) ----------------
__global__ __launch_bounds__(256) void cast_k(const float* __restrict__ in,
                                              unsigned short* __restrict__ out, int n4) {
  int i = blockIdx.x * 256 + threadIdx.x;
  if (i < n4) {
    float4 v = *(const float4*)(in + (size_t)i * 4);
    u16x4 o; o.x = f2bf(v.x); o.y = f2bf(v.y); o.z = f2bf(v.z); o.w = f2bf(v.w);
    *(u16x4*)(out + (size_t)i * 4) = o;
  }
}

// ---------------- projection GEMM: C = A(M,K) @ W(N,K)^T, bf16, 128x128 tile ----------------
// which==0: q (PRE-SCALED by QSCALE) -> (b,h,s,c); which==1: k -> (b,h,s,c);
// which==2: v -> V^T (b,h,c,s) via LDS transpose.
// Staging: global_load_lds(16) with pre-swizzled global source, linear LDS dest.
__global__ __launch_bounds__(256) void gemm_proj_k(
    const unsigned short* __restrict__ qln, const unsigned short* __restrict__ kvln,
    const unsigned short* __restrict__ Wq,  const unsigned short* __restrict__ Wk,
    const unsigned short* __restrict__ Wv,
    unsigned short* __restrict__ qb, unsigned short* __restrict__ kb,
    unsigned short* __restrict__ vtb) {
  const int K = D_;
  int which = blockIdx.z;
  const unsigned short* A = (which == 0) ? qln : kvln;
  const unsigned short* W = (which == 0) ? Wq : (which == 1 ? Wk : Wv);
  unsigned short* O = (which == 0) ? qb : (which == 1 ? kb : vtb);
  int m0 = blockIdx.y * 128, n0 = blockIdx.x * 128;
  __shared__ __align__(16) char psm[128 * 272];   // lsA(16K)+lsB(16K) | V^T transpose buffer
  char* lsA = psm;
  char* lsB = psm + 16384;
  int tid = threadIdx.x, l = tid & 63, w = tid >> 6;
  int wm = (w >> 1) * 64, wn = (w & 1) * 64;
  f32x4 acc[4][4] = {};
  for (int kt = 0; kt < K; kt += 64) {
    __syncthreads();
#pragma unroll
    for (int i = 0; i < 4; i++) {                    // stage A,B via async DMA (4+4 calls/wave)
      int rbase = (i * 4 + w) * 8;
      int row = rbase + (l >> 3), c8 = l & 7;
      int sc = (c8 ^ (row & 7)) * 8;
      gload16(A + (size_t)(m0 + row) * K + kt + sc, lsA + rbase * 128);
      gload16(W + (size_t)(n0 + row) * K + kt + sc, lsB + rbase * 128);
    }
    __syncthreads();
#pragma unroll
    for (int kk = 0; kk < 2; kk++) {
      bf16x8 af[4], bfr[4];
      int koff = kk * 64 + (l >> 4) * 16;
#pragma unroll
      for (int mf = 0; mf < 4; mf++) {
        int row = wm + mf * 16 + (l & 15);
        af[mf] = *(const bf16x8*)(lsA + row * 128 + (koff ^ ((row & 7) << 4)));
      }
#pragma unroll
      for (int nf = 0; nf < 4; nf++) {
        int row = wn + nf * 16 + (l & 15);
        bfr[nf] = *(const bf16x8*)(lsB + row * 128 + (koff ^ ((row & 7) << 4)));
      }
#pragma unroll
      for (int mf = 0; mf < 4; mf++)
#pragma unroll
        for (int nf = 0; nf < 4; nf++)
          acc[mf][nf] = __builtin_amdgcn_mfma_f32_16x16x32_bf16(af[mf], bfr[nf], acc[mf][nf], 0, 0, 0);
    }
  }
  // epilogue: C/D layout col=lane&15, row=(lane>>4)*4+reg
  if (which < 2) {
    float sc = (which == 0) ? QSCALE : 1.0f;
#pragma unroll
    for (int mf = 0; mf < 4; mf++)
#pragma unroll
      for (int nf = 0; nf < 4; nf++)
#pragma unroll
        for (int r = 0; r < 4; r++) {
          int gm = m0 + wm + mf * 16 + (l >> 4) * 4 + r;
          int gn = n0 + wn + nf * 16 + (l & 15);
          int b = gm >> 10, s = gm & 1023;
          int h = gn >> 7,  c = gn & 127;
          O[((size_t)((b * H_ + h) * S_ + s)) * C2_ + c] = f2bf(acc[mf][nf][r] * sc);
        }
  } else {
    // V^T: bf16 tile -> LDS [feat 128][s 128] (272B stride), read rows, store coalesced
    __syncthreads();
#pragma unroll
    for (int mf = 0; mf < 4; mf++)
#pragma unroll
      for (int nf = 0; nf < 4; nf++) {
        int crow = wn + nf * 16 + (l & 15);          // tile-local feature
        int sloc = wm + mf * 16 + (l >> 4) * 4;      // tile-local s (r packs 0..3)
        u16x4 pk4;
        pk4.x = f2bf(acc[mf][nf][0]); pk4.y = f2bf(acc[mf][nf][1]);
        pk4.z = f2bf(acc[mf][nf][2]); pk4.w = f2bf(acc[mf][nf][3]);
        *(u16x4*)(psm + (size_t)crow * 272 + sloc * 2) = pk4;
      }
    __syncthreads();
    int b = m0 >> 10, sbase = m0 & 1023;
#pragma unroll
    for (int i = 0; i < 8; i++) {
      int u2 = i * 256 + tid;
      int row = u2 >> 4, c16 = u2 & 15;
      u16x8 vv = *(const u16x8*)(psm + (size_t)row * 272 + c16 * 16);
      int gn = n0 + row, h = gn >> 7, cfeat = gn & 127;
      *(u16x8*)(O + ((size_t)((b * H_ + h) * C2_ + cfeat)) * S_ + sbase + c16 * 8) = vv;
    }
  }
}

// ---------------- output GEMM: out = A(4096,2048) @ Wo(1024,2048)^T + resid ----------------
__global__ __launch_bounds__(256) void gemm_out_k(
    const unsigned short* __restrict__ A, const unsigned short* __restrict__ W,
    const float* __restrict__ resid, float* __restrict__ out) {
  const int K = E_;
  int m0 = blockIdx.y * 128, n0 = blockIdx.x * 128;
  __shared__ __align__(16) char psm2[32768];      // lsA(16K) + lsB(16K)  [R4 bug: was 16K total]
  char* lsA = psm2;
  char* lsB = psm2 + 16384;
  int tid = threadIdx.x, l = tid & 63, w = tid >> 6;
  int wm = (w >> 1) * 64, wn = (w & 1) * 64;
  f32x4 acc[4][4] = {};
  for (int kt = 0; kt < K; kt += 64) {
    __syncthreads();
#pragma unroll
    for (int i = 0; i < 4; i++) {
      int rbase = (i * 4 + w) * 8;
      int row = rbase + (l >> 3), c8 = l & 7;
      int sc = (c8 ^ (row & 7)) * 8;
      gload16(A + (size_t)(m0 + row) * K + kt + sc, lsA + rbase * 128);
      gload16(W + (size_t)(n0 + row) * K + kt + sc, lsB + rbase * 128);
    }
    __syncthreads();
#pragma unroll
    for (int kk = 0; kk < 2; kk++) {
      bf16x8 af[4], bfr[4];
      int koff = kk * 64 + (l >> 4) * 16;
#pragma unroll
      for (int mf = 0; mf < 4; mf++) {
        int row = wm + mf * 16 + (l & 15);
        af[mf] = *(const bf16x8*)(lsA + row * 128 + (koff ^ ((row & 7) << 4)));
      }
#pragma unroll
      for (int nf = 0; nf < 4; nf++) {
        int row = wn + nf * 16 + (l & 15);
        bfr[nf] = *(const bf16x8*)(lsB + row * 128 + (koff ^ ((row & 7) << 4)));
      }
#pragma unroll
      for (int mf = 0; mf < 4; mf++)
#pragma unroll
        for (int nf = 0; nf < 4; nf++)
          acc[mf][nf] = __builtin_amdgcn_mfma_f32_16x16x32_bf16(af[mf], bfr[nf], acc[mf][nf], 0, 0, 0);
    }
  }
#pragma unroll
  for (int mf = 0; mf < 4; mf++)
#pragma unroll
    for (int nf = 0; nf < 4; nf++)
#pragma unroll
      for (int r = 0; r < 4; r++) {
        int gm = m0 + wm + mf * 16 + (l >> 4) * 4 + r;
        int gn = n0 + wn + nf * 16 + (l & 15);
        size_t idx = (size_t)gm * D_ + gn;
        out[idx] = acc[mf][nf][r] + resid[idx];
      }
}

// ---------------- differential flash attention + head LN (v5) ----------------
// Swapped QK^T + in-reg P (permlane32 + PROVEN shfl16-select) + static max
// (Q pre-scaled, P=exp2(S)) + ones-MFMA row-sums + double-buffered global_load_lds.
__global__ __launch_bounds__(256) void attn_k(
    const unsigned short* __restrict__ q, const unsigned short* __restrict__ k,
    const unsigned short* __restrict__ vt,
    const float* __restrict__ lq1, const float* __restrict__ lk1,
    const float* __restrict__ lq2, const float* __restrict__ lk2,
    const float* __restrict__ hng, const float* __restrict__ hnb,
    const float* __restrict__ lambda_init, const int* __restrict__ dis2,
    unsigned short* __restrict__ out) {
  int bh = blockIdx.x;   // 0..63 (x-major -> XCD = bh%8: all q-tiles of a head share an XCD)
  int qt = blockIdx.y;   // 0..15
  int tid = threadIdx.x, ln = tid & 63, w = tid >> 6;
  int g = ln >> 4, c = ln & 15;
  bool godd = (g & 1);
  __shared__ unsigned short lsK[2][64 * 128];    // [key][feat] 256B rows, src-swizzled
  __shared__ unsigned short lsVt[2][128 * 64];   // [feat][key] 128B rows, src-swizzled
  __shared__ float s_lam, s_osc;

  if (tid < 64) {                             // lambda scalar (wave 0)
    float a = lq1[ln] * lk1[ln];
    float cc = lq2[ln] * lk2[ln];
#pragma unroll
    for (int m = 32; m; m >>= 1) { a += __shfl_xor(a, m, 64); cc += __shfl_xor(cc, m, 64); }
    if (ln == 0) {
      float li = lambda_init[0];
      float lam = __expf(a) - __expf(cc) + li;
      if (dis2[0] != 0) lam = 0.f;
      s_lam = lam;
      s_osc = 1.f - li;
    }
  }

  const unsigned short* kbh = k + (size_t)bh * S_ * C2_;
  const unsigned short* vbh = vt + (size_t)bh * C2_ * S_;

  // Q as B-frags: col=lane&15 -> q-row, k=g*8+j -> feature (values pre-scaled by QSCALE)
  int qrow = qt * 64 + w * 16 + c;
  const unsigned short* qrp = q + ((size_t)bh * S_ + qrow) * C2_;
  bf16x8 qf[2][2];
#pragma unroll
  for (int t = 0; t < 2; t++)
#pragma unroll
    for (int kk = 0; kk < 2; kk++)
      qf[t][kk] = *(const bf16x8*)(qrp + t * 64 + kk * 32 + g * 8);

  f32x4 lones[2] = {};
  f32x4 o[2][8] = {};
  bf16x8 onesf;
#pragma unroll
  for (int j = 0; j < 8; j++) onesf[j] = (short)0x3F80;   // bf16 1.0

  // ---- staging: wave-cooperative async DMA, pre-swizzled source, linear LDS ----
#define STAGE_KV(buf, t0s)                                                            \
  {                                                                                   \
    const unsigned short* kbase = kbh + (size_t)(t0s) * C2_;                          \
    _Pragma("unroll")                                                                 \
    for (int i = 0; i < 4; i++) {                                                     \
      int rb = w * 16 + i * 4;                                                        \
      int row = rb + (ln >> 4), c16 = ln & 15;                                        \
      gload16(kbase + row * C2_ + ((c16 ^ (row & 7)) * 8),                            \
              (char*)&lsK[buf][0] + rb * 256);                                        \
    }                                                                                 \
    const unsigned short* vbase = vbh + (t0s);                                        \
    _Pragma("unroll")                                                                 \
    for (int i = 0; i < 4; i++) {                                                     \
      int rb = w * 32 + i * 8;                                                        \
      int row = rb + (ln >> 3), c8 = ln & 7;                                          \
      gload16(vbase + (size_t)row * S_ + ((c8 ^ (row & 7)) * 8),                      \
              (char*)&lsVt[buf][0] + rb * 128);                                       \
    }                                                                                 \
  }

  STAGE_KV(0, 0);
  __syncthreads();                             // vmcnt drained by compiler: buf0 ready

  for (int it = 0; it < S_ / 64; ++it) {
    int cur = it & 1;
    if (it + 1 < S_ / 64) STAGE_KV(cur ^ 1, (it + 1) * 64);

    unsigned int paw[2][2][4];                 // [term][kk][word] P A-frags

#pragma unroll
    for (int term = 0; term < 2; term++) {
      f32x4 sf[4] = {};                        // sf[nf]: keys nf*16+g*4+r, q=c
      __builtin_amdgcn_s_setprio(1);
#pragma unroll
      for (int kk = 0; kk < 2; kk++) {
#pragma unroll
        for (int nf = 0; nf < 4; nf++) {
          int kfrow = nf * 16 + c;
          bf16x8 kf = *(const bf16x8*)((char*)&lsK[cur][0] + kfrow * 256 +
                        ((term * 128 + kk * 64 + g * 16) ^ ((kfrow & 7) << 4)));
          sf[nf] = __builtin_amdgcn_mfma_f32_16x16x32_bf16(kf, qf[term][kk], sf[nf], 0, 0, 0);
        }
      }
      __builtin_amdgcn_s_setprio(0);
      // P = exp2(S) (static max; Q pre-scaled into log2 domain)
#pragma unroll
      for (int nf = 0; nf < 4; nf++)
#pragma unroll
        for (int r = 0; r < 4; r++)
          sf[nf][r] = exp2f(sf[nf][r]);
      // pack P -> bf16 A-frags: permlane32_swap + shfl16-select (R3-proven)
#pragma unroll
      for (int kk = 0; kk < 2; kk++) {
        unsigned int X0 = cvtpk_bf16(sf[2 * kk][0], sf[2 * kk][1]);
        unsigned int X1 = cvtpk_bf16(sf[2 * kk][2], sf[2 * kk][3]);
        unsigned int Y0 = cvtpk_bf16(sf[2 * kk + 1][0], sf[2 * kk + 1][1]);
        unsigned int Y1 = cvtpk_bf16(sf[2 * kk + 1][2], sf[2 * kk + 1][3]);
        asm("v_permlane32_swap_b32 %0, %1" : "+v"(X0), "+v"(Y0));   // g01 <-> g23 halves
        asm("v_permlane32_swap_b32 %0, %1" : "+v"(X1), "+v"(Y1));
        {                                                           // 16-swap via shfl+select
          unsigned int t0w = __shfl_xor((int)Y0, 16), u0 = __shfl_xor((int)X0, 16);
          unsigned int t1w = __shfl_xor((int)Y1, 16), u1 = __shfl_xor((int)X1, 16);
          unsigned int nX0 = godd ? t0w : X0, nY0 = godd ? Y0 : u0;
          unsigned int nX1 = godd ? t1w : X1, nY1 = godd ? Y1 : u1;
          paw[term][kk][0] = nX0; paw[term][kk][1] = nX1;
          paw[term][kk][2] = nY0; paw[term][kk][3] = nY1;
        }
      }
    }

    // PV both terms; V frags read once; row-sums via ones-MFMA (lands in O layout)
#pragma unroll
    for (int kk = 0; kk < 2; kk++) {
      union { unsigned int u[4]; bf16x8 v; } pa0, pa1;
#pragma unroll
      for (int j = 0; j < 4; j++) { pa0.u[j] = paw[0][kk][j]; pa1.u[j] = paw[1][kk][j]; }
      __builtin_amdgcn_s_setprio(1);
      lones[0] = __builtin_amdgcn_mfma_f32_16x16x32_bf16(pa0.v, onesf, lones[0], 0, 0, 0);
      lones[1] = __builtin_amdgcn_mfma_f32_16x16x32_bf16(pa1.v, onesf, lones[1], 0, 0, 0);
#pragma unroll
      for (int nf2 = 0; nf2 < 8; nf2++) {
        int vrow = nf2 * 16 + c;
        bf16x8 vf = *(const bf16x8*)((char*)&lsVt[cur][0] + vrow * 128 +
                      ((kk * 64 + g * 16) ^ ((vrow & 7) << 4)));
        o[0][nf2] = __builtin_amdgcn_mfma_f32_16x16x32_bf16(pa0.v, vf, o[0][nf2], 0, 0, 0);
        o[1][nf2] = __builtin_amdgcn_mfma_f32_16x16x32_bf16(pa1.v, vf, o[1][nf2], 0, 0, 0);
      }
      __builtin_amdgcn_s_setprio(0);
    }
    __syncthreads();   // reads of buf[cur] done; next-buf DMA drained (compiler vmcnt)
  }

  // epilogue: combine terms, head-LN over 128, scale, store bf16 (B,S,2048)
  float lam = s_lam, osc = s_osc;
  int b = bh >> 4, h = bh & 15;
#pragma unroll
  for (int r = 0; r < 4; r++) {
    float inv1 = 1.f / lones[0][r];
    float inv2 = lam / lones[1][r];
    float vals[8];
    float sum = 0.f, sq = 0.f;
#pragma unroll
    for (int nf2 = 0; nf2 < 8; nf2++) {
      float vv = o[0][nf2][r] * inv1 - o[1][nf2][r] * inv2;
      vals[nf2] = vv;
      sum += vv; sq += vv * vv;
    }
    sum = red16_sum(sum);
    sq  = red16_sum(sq);
    float mean = sum * (1.f / 128.f);
    float var  = sq * (1.f / 128.f) - mean * mean;
    float rstd = rsqrtf(var + 1e-5f);
    int srow = qt * 64 + w * 16 + g * 4 + r;
    unsigned short* orow = out + ((size_t)(b * S_ + srow)) * E_ + h * C2_;
#pragma unroll
    for (int nf2 = 0; nf2 < 8; nf2++) {
      int feat = nf2 * 16 + c;
      float y = (vals[nf2] - mean) * rstd * hng[feat] + hnb[feat];
      orow[feat] = f2bf(y * osc);
    }
  }
}

// ---------------- host launcher ----------------
extern "C" void kernel_launch(void* const* d_in, const int* in_sizes, int n_in,
                              void* d_out, int out_size, void* d_ws, size_t ws_size,
                              hipStream_t stream) {
  const float* qtok = (const float*)d_in[0];
  const float* kvtok = (const float*)d_in[1];
  const float* lnqg = (const float*)d_in[2];
  const float* lnqb = (const float*)d_in[3];
  const float* lnkg = (const float*)d_in[4];
  const float* lnkb = (const float*)d_in[5];
  const float* Wq = (const float*)d_in[6];
  const float* Wk = (const float*)d_in[7];
  const float* Wv = (const float*)d_in[8];
  const float* Wo = (const float*)d_in[9];
  const float* lq1 = (const float*)d_in[10];
  const float* lk1 = (const float*)d_in[11];
  const float* lq2 = (const float*)d_in[12];
  const float* lk2 = (const float*)d_in[13];
  const float* hng = (const float*)d_in[14];
  const float* hnb = (const float*)d_in[15];
  const float* lami = (const float*)d_in[16];
  const int*   dis2 = (const int*)d_in[17];
  float* outp = (float*)d_out;

  char* ws = (char*)d_ws;
  const size_t MB = 1024 * 1024;
  unsigned short* qln    = (unsigned short*)(ws + 0);
  unsigned short* kvln   = (unsigned short*)(ws + 8 * MB);
  unsigned short* attn_o = (unsigned short*)(ws + 0);        // aliases qln/kvln (dead by then)
  unsigned short* Wqb = (unsigned short*)(ws + 16 * MB);
  unsigned short* Wkb = (unsigned short*)(ws + 20 * MB);
  unsigned short* Wvb = (unsigned short*)(ws + 24 * MB);
  unsigned short* Wob = (unsigned short*)(ws + 28 * MB);
  unsigned short* qb  = (unsigned short*)(ws + 32 * MB);
  unsigned short* kb  = (unsigned short*)(ws + 48 * MB);
  unsigned short* vtb = (unsigned short*)(ws + 64 * MB);

  ln_cast_k<<<dim3(4096), dim3(256), 0, stream>>>(qtok, lnqg, lnqb, qln);
  ln_cast_k<<<dim3(4096), dim3(256), 0, stream>>>(kvtok, lnkg, lnkb, kvln);
  cast_k<<<dim3(2048), dim3(256), 0, stream>>>(Wq, Wqb, 512 * 1024);
  cast_k<<<dim3(2048), dim3(256), 0, stream>>>(Wk, Wkb, 512 * 1024);
  cast_k<<<dim3(2048), dim3(256), 0, stream>>>(Wv, Wvb, 512 * 1024);
  cast_k<<<dim3(2048), dim3(256), 0, stream>>>(Wo, Wob, 512 * 1024);
  gemm_proj_k<<<dim3(16, 32, 3), dim3(256), 0, stream>>>(qln, kvln, Wqb, Wkb, Wvb, qb, kb, vtb);
  attn_k<<<dim3(64, 16), dim3(256), 0, stream>>>(qb, kb, vtb, lq1, lk1, lq2, lk2,
                                                 hng, hnb, lami, dis2, attn_o);
  gemm_out_k<<<dim3(8, 32), dim3(256), 0, stream>>>(attn_o, Wob, qtok, outp);
}